// Round 2
// baseline (306.866 us; speedup 1.0000x reference)
//
#include <hip/hip_runtime.h>
#include <hip/hip_bf16.h>

// B=1024, D_IN=64, H=128, D_OUT=16
// inputs:  fp32  x[1024,64] W1[64,128] b1[128] W2[128,16] b2[16]
// outputs: fp32, flat: f[1024*16] | df[1024*64*16] | d2f[1024*64*64*16]
// ws (bf16): U[4096*128] (U[(k*64+i)][h] = W1[i,h]*W1[k,h]) | Gt[1024*16*128] (Gt[b][j][h] = t_bh*W2[h,j])
//
// Math per sample: z = x@W1+b1, a=tanh(z), s=1-a^2, t=-2*a*s
//   f          = a@W2 + b2
//   df[i,j]    = sum_h W1[i,h] s_h W2[h,j]
//   d2f[k,i,j] = sum_h W1[i,h] W1[k,h] t_h W2[h,j]   (symmetric in i,k)
// d2f_b = (W1 (x) W1) [4096x128] @ (t_b*W2) [128x16]  -> bf16 MFMA batched GEMM, fp32 out.

typedef unsigned short u16;
typedef short s8v __attribute__((ext_vector_type(8)));   // 8 bf16 = 4 VGPRs (A/B frag)
typedef float f4v __attribute__((ext_vector_type(4)));

__device__ __forceinline__ u16 f2bf(float f){
  __hip_bfloat16 h = __float2bfloat16(f);   // RNE
  return __builtin_bit_cast(u16, h);
}

// ---------------- K1: per-sample z,a,s,t ; f ; df ; emit Gt and a slice of U ----------------
__global__ __launch_bounds__(128) void k1_fdf(
    const float* __restrict__ x,  const float* __restrict__ W1, const float* __restrict__ b1,
    const float* __restrict__ W2, const float* __restrict__ b2,
    float* __restrict__ f_out, float* __restrict__ df_out,
    u16* __restrict__ U, u16* __restrict__ Gt)
{
  const int b   = blockIdx.x;   // sample
  const int tid = threadIdx.x;  // 0..127

  __shared__ float sx[64];
  __shared__ float s_a[128];
  __shared__ float s_sw2[128 * 16];   // s_h * W2[h][j]

  // U slice: 512 elements [b*512, b*512+512): U[r][h] = W1[r&63][h]*W1[r>>6][h]
  // (cached stores on purpose: k2 reads U/Gt, keep them in cache hierarchy)
  {
    const int base = b * 512;
#pragma unroll
    for (int u = 0; u < 4; ++u){
      int idx = base + u*128 + tid;
      int r = idx >> 7, h = idx & 127;
      float w = W1[(r & 63)*128 + h] * W1[(r >> 6)*128 + h];
      U[idx] = f2bf(w);
    }
  }

  if (tid < 64) sx[tid] = x[b*64 + tid];
  __syncthreads();

  // z_h for h = tid (W1 column read coalesced across threads)
  float z = b1[tid];
#pragma unroll 8
  for (int i = 0; i < 64; ++i) z += sx[i] * W1[i*128 + tid];
  float a = tanhf(z);
  float s = 1.0f - a*a;        // tanh'
  float t = -2.0f * a * s;     // tanh''
  s_a[tid] = a;
#pragma unroll
  for (int j = 0; j < 16; ++j){
    float w2 = W2[tid*16 + j];
    s_sw2[tid*16 + j] = s * w2;
    Gt[(b*16 + j)*128 + tid] = f2bf(t * w2);   // [b][j][h], h contiguous (B-frag order)
  }
  __syncthreads();

  // f[b,j], j = tid (first 16 lanes); f is never re-read -> nontemporal
  if (tid < 16){
    float acc = b2[tid];
    for (int h = 0; h < 128; ++h) acc += s_a[h] * W2[h*16 + tid];
    __builtin_nontemporal_store(acc, &f_out[b*16 + tid]);
  }

  // df[b,i,j] = sum_h W1[i,h] * (s*W2)[h,j] ; thread -> (i = tid>>1, j0 = (tid&1)*8)
  const int i  = tid >> 1;
  const int j0 = (tid & 1) * 8;
  float acc[8] = {0,0,0,0,0,0,0,0};
  for (int h0 = 0; h0 < 128; h0 += 8){
    const float4* wp = (const float4*)&W1[i*128 + h0];
    float4 wa = wp[0], wb = wp[1];
    float wf[8] = {wa.x, wa.y, wa.z, wa.w, wb.x, wb.y, wb.z, wb.w};
#pragma unroll
    for (int hh = 0; hh < 8; ++hh){
      const float4* sp = (const float4*)&s_sw2[(h0 + hh)*16 + j0];
      float4 A = sp[0], Bv = sp[1];
      float w1 = wf[hh];
      acc[0] += w1*A.x;  acc[1] += w1*A.y;  acc[2] += w1*A.z;  acc[3] += w1*A.w;
      acc[4] += w1*Bv.x; acc[5] += w1*Bv.y; acc[6] += w1*Bv.z; acc[7] += w1*Bv.w;
    }
  }
  // df is never re-read -> nontemporal (don't pollute L2 before k2 runs)
  f4v v0 = {acc[0], acc[1], acc[2], acc[3]};
  f4v v1 = {acc[4], acc[5], acc[6], acc[7]};
  float* dp = &df_out[b*1024 + i*16 + j0];
  __builtin_nontemporal_store(v0, (f4v*)dp);
  __builtin_nontemporal_store(v1, (f4v*)(dp + 4));
}

// ---------------- K2: d2f[b] (4096x16) = U (4096x128) @ G_b (128x16), bf16 MFMA, fp32 out ----
// block = 256 thr (4 waves), handles 4 samples x 1024 U-rows. grid = (256 bgroups, 4 row-chunks)
// OPERAND-SWAPPED MFMA: acc = mfma(B, A) computes (U@G)^T per 16x16 tile, so each lane holds
// 4 CONSECUTIVE j values -> one dwordx4 store per (s,mt), 1KiB fully coalesced per wave-instr.
// Stores are NONTEMPORAL so the 256MiB d2f stream does not evict U/Gt from L2
// (U is re-read by all 256 b-groups; keeping it L2-resident removes ~256MB of HBM re-reads).
__global__ __launch_bounds__(256) void k2_d2f(
    const u16* __restrict__ U, const u16* __restrict__ Gt, float* __restrict__ d2f)
{
  const int tid  = threadIdx.x;
  const int lane = tid & 63;
  const int wave = tid >> 6;
  const int n = lane & 15;      // MFMA (row of A' / col of B') position
  const int q = lane >> 4;      // quad (K-block)
  const int b0 = blockIdx.x * 4;
  const int mb = blockIdx.y;

  // G-fragments: all K=128 for 4 samples, held in registers (64 VGPRs)
  // lane n holds Gt[b][j=n][h=q*8 + ks*32 + e]  == A'[m=n][k] with A' = G^T
  s8v bfrag[4][4];
#pragma unroll
  for (int s = 0; s < 4; ++s){
    const u16* gp = Gt + ((b0 + s)*16 + n)*128 + q*8;
#pragma unroll
    for (int ks = 0; ks < 4; ++ks)
      bfrag[s][ks] = *(const s8v*)(gp + ks*32);
  }

  const int R0 = mb*1024 + wave*256;   // 16 m-tiles of 16 rows per wave
#pragma unroll 2
  for (int mt = 0; mt < 16; ++mt){
    const int rowbase = R0 + mt*16;
    // lane n holds U[rowbase+n][q*8 + ks*32 + e] == B'[k][col=n] with B' = U_tile^T
    const u16* ap = U + (rowbase + n)*128 + q*8;
    s8v afrag[4];
#pragma unroll
    for (int ks = 0; ks < 4; ++ks)
      afrag[ks] = *(const s8v*)(ap + ks*32);

#pragma unroll
    for (int s = 0; s < 4; ++s){
      f4v acc = {0.f, 0.f, 0.f, 0.f};
#pragma unroll
      for (int ks = 0; ks < 4; ++ks)
        acc = __builtin_amdgcn_mfma_f32_16x16x32_bf16(bfrag[s][ks], afrag[ks], acc, 0, 0, 0);
      // D' = (U_tile @ G)^T : D'[row=q*4+reg][col=n] = d2f_tile[row n][j=q*4+reg]
      // -> lane (n,q) writes d2f[b0+s][rowbase+n][j = q*4 .. q*4+3] as one float4
      float* op = d2f + (size_t)(b0 + s)*65536 + (size_t)(rowbase + n)*16 + q*4;
      __builtin_nontemporal_store(acc, (f4v*)op);
    }
  }
}

extern "C" void kernel_launch(void* const* d_in, const int* in_sizes, int n_in,
                              void* d_out, int out_size, void* d_ws, size_t ws_size,
                              hipStream_t stream)
{
  (void)in_sizes; (void)n_in; (void)out_size; (void)ws_size;
  const float* x  = (const float*)d_in[0];
  const float* W1 = (const float*)d_in[1];
  const float* b1 = (const float*)d_in[2];
  const float* W2 = (const float*)d_in[3];
  const float* b2 = (const float*)d_in[4];

  float* out     = (float*)d_out;
  float* f_out   = out;                    // 16384
  float* df_out  = out + 16384;            // 1048576
  float* d2f_out = out + 1064960;          // 67108864

  u16* U  = (u16*)d_ws;                    // 524288 bf16 = 1 MB
  u16* Gt = U + 524288;                    // 2097152 bf16 = 4 MB

  k1_fdf<<<1024, 128, 0, stream>>>(x, W1, b1, W2, b2, f_out, df_out, U, Gt);
  k2_d2f<<<dim3(256, 4), 256, 0, stream>>>(U, Gt, d2f_out);
}

// Round 3
// 298.867 us; speedup vs baseline: 1.0268x; 1.0268x over previous
//
#include <hip/hip_runtime.h>
#include <hip/hip_bf16.h>

// B=1024, D_IN=64, H=128, D_OUT=16
// inputs:  fp32  x[1024,64] W1[64,128] b1[128] W2[128,16] b2[16]
// outputs: fp32, flat: f[1024*16] | df[1024*64*16] | d2f[1024*64*64*16]
//
// Math per sample: z = x@W1+b1, a=tanh(z), s=1-a^2, t=-2*a*s
//   f          = a@W2 + b2
//   df[i,j]    = sum_h W1[i,h] s_h W2[h,j]
//   d2f[k,i,j] = sum_h W1[i,h] W1[k,h] t_h W2[h,j]
//
// FUSED d2f: no workspace, no k1->k2 serialization. Each block recomputes
// its 4 samples' G = t*W2 (cheap tanh pass) and synthesizes A-fragments
// U[r][h] = W1[i][h]*W1[k][h] on the fly from LDS-resident f32 W1.
// Numerics of d2f are IDENTICAL to the previous passing version
// (same f32 products -> bf16 RNE -> same MFMA order).

typedef unsigned short u16;
typedef short s8v __attribute__((ext_vector_type(8)));   // 8 bf16 = 4 VGPRs (A/B frag)
typedef float f4v __attribute__((ext_vector_type(4)));

__device__ __forceinline__ u16 f2bf(float f){
  __hip_bfloat16 h = __float2bfloat16(f);   // RNE
  return __builtin_bit_cast(u16, h);
}

#define W1S 132   // padded LDS stride for W1 rows: 132 mod 32 = 4 -> balanced banks

// ---------------- K2 fused: d2f[b] (4096x16) = (W1 (x) W1) @ (t_b*W2) ----------------
// grid = dim3(256 bgroups, 2 row-halves), block = 256 thr (4 waves).
// Each block: 4 samples x 2048 U-rows. LDS = 33.8K (W1 f32) + 16K (G bf16) + 1K (x) = 51K
// -> 2 blocks/CU resident, 8 waves/CU. Store-BW-bound by design (256MB NT d2f stream).
__global__ __launch_bounds__(256) void k2_fused(
    const float* __restrict__ x, const float* __restrict__ W1, const float* __restrict__ b1,
    const float* __restrict__ W2, float* __restrict__ d2f)
{
  const int tid  = threadIdx.x;
  const int lane = tid & 63;
  const int wave = tid >> 6;
  const int n = lane & 15;      // MFMA position
  const int q = lane >> 4;      // quad (K-block)
  const int b0 = blockIdx.x * 4;
  const int mb = blockIdx.y;

  __shared__ float sW1[64 * W1S];   // f32 W1, padded rows
  __shared__ u16   sG[4 * 2048];    // per sample: bytes (j*256 + h*2) ^ ((j&7)<<4)
  __shared__ float sx[256];         // x for 4 samples

  // ---- stage W1 (8192 floats, 8 x float4 per thread) and x ----
#pragma unroll
  for (int v = 0; v < 8; ++v){
    int idx = v*256 + tid;              // float4 index 0..2047
    int r = idx >> 5;                   // row (32 float4 per row)
    int c = (idx & 31) << 2;            // col
    *(f4v*)&sW1[r*W1S + c] = *(const f4v*)&W1[r*128 + c];
  }
  sx[tid] = x[b0*64 + tid];
  __syncthreads();

  // ---- z, a, t -> sG (bf16, XOR-swizzled rows) ----
#pragma unroll
  for (int it = 0; it < 2; ++it){
    int idx = it*256 + tid;             // (s,h) item, 512 total
    int s = idx >> 7;
    int h = idx & 127;
    float z = b1[h];
#pragma unroll 8
    for (int i = 0; i < 64; ++i) z += sx[s*64 + i] * sW1[i*W1S + h];
    float a = tanhf(z);
    float t = -2.0f * a * (1.0f - a*a);
    f4v w2r[4];
#pragma unroll
    for (int v2 = 0; v2 < 4; ++v2) w2r[v2] = *(const f4v*)&W2[h*16 + v2*4];
#pragma unroll
    for (int j = 0; j < 16; ++j){
      int byte = (j*256 + h*2) ^ ((j & 7) << 4);   // swizzle: spread row j across banks
      sG[s*2048 + (byte >> 1)] = f2bf(t * w2r[j >> 2][j & 3]);
    }
  }
  __syncthreads();

  // ---- B-fragments (G^T) from sG: lane(n,q), ks -> Gt[s][j=n][h=q*8+ks*32+e] ----
  // read addr uses the same XOR involution; +2e (e<8) never carries into bit 4.
  s8v bfrag[4][4];
#pragma unroll
  for (int s = 0; s < 4; ++s){
#pragma unroll
    for (int ks = 0; ks < 4; ++ks){
      int byte = (n*256 + q*16 + ks*64) ^ ((n & 7) << 4);
      bfrag[s][ks] = *(const s8v*)&sG[s*2048 + (byte >> 1)];
    }
  }

  // ---- main loop: A-frag on the fly, operand-swapped MFMA, NT dwordx4 store ----
  const int R0 = mb*2048 + wave*512;    // each wave: 512 rows = 32 m-tiles
#pragma unroll 2
  for (int mt = 0; mt < 32; ++mt){
    const int rowbase = R0 + mt*16;
    const int r = rowbase + n;          // U row
    const int i = r & 63;               // varies per lane -> padded-stride reads
    const int k = r >> 6;               // uniform across the 16-row tile -> broadcast
    const float* wi = &sW1[i*W1S];
    const float* wk = &sW1[k*W1S];
    s8v afrag[4];
#pragma unroll
    for (int ks = 0; ks < 4; ++ks){
      int c = q*8 + ks*32;
      f4v ia = *(const f4v*)&wi[c];
      f4v ib = *(const f4v*)&wi[c+4];
      f4v ka = *(const f4v*)&wk[c];
      f4v kb = *(const f4v*)&wk[c+4];
      s8v av;
#pragma unroll
      for (int e = 0; e < 4; ++e) av[e]   = (short)f2bf(ia[e]*ka[e]);
#pragma unroll
      for (int e = 0; e < 4; ++e) av[4+e] = (short)f2bf(ib[e]*kb[e]);
      afrag[ks] = av;
    }
#pragma unroll
    for (int s = 0; s < 4; ++s){
      f4v acc = {0.f, 0.f, 0.f, 0.f};
#pragma unroll
      for (int ks = 0; ks < 4; ++ks)
        acc = __builtin_amdgcn_mfma_f32_16x16x32_bf16(bfrag[s][ks], afrag[ks], acc, 0, 0, 0);
      // D' = (U@G)^T: lane(n,q) holds d2f[b0+s][rowbase+n][q*4 .. q*4+3] -> one NT dwordx4
      float* op = d2f + (size_t)(b0 + s)*65536 + (size_t)(rowbase + n)*16 + q*4;
      __builtin_nontemporal_store(acc, (f4v*)op);
    }
  }
}

// ---------------- K1 lite: f and df only (fp32 exact, unchanged numerics) ----------------
__global__ __launch_bounds__(128) void k1_fdf(
    const float* __restrict__ x,  const float* __restrict__ W1, const float* __restrict__ b1,
    const float* __restrict__ W2, const float* __restrict__ b2,
    float* __restrict__ f_out, float* __restrict__ df_out)
{
  const int b   = blockIdx.x;   // sample
  const int tid = threadIdx.x;  // 0..127

  __shared__ float sx[64];
  __shared__ float s_a[128];
  __shared__ float s_sw2[128 * 16];   // s_h * W2[h][j]

  if (tid < 64) sx[tid] = x[b*64 + tid];
  __syncthreads();

  // z_h for h = tid (W1 column read coalesced across threads)
  float z = b1[tid];
#pragma unroll 8
  for (int i = 0; i < 64; ++i) z += sx[i] * W1[i*128 + tid];
  float a = tanhf(z);
  float s = 1.0f - a*a;        // tanh'
  s_a[tid] = a;
#pragma unroll
  for (int j = 0; j < 16; ++j)
    s_sw2[tid*16 + j] = s * W2[tid*16 + j];
  __syncthreads();

  // f[b,j], j = tid (first 16 lanes); never re-read -> nontemporal
  if (tid < 16){
    float acc = b2[tid];
    for (int h = 0; h < 128; ++h) acc += s_a[h] * W2[h*16 + tid];
    __builtin_nontemporal_store(acc, &f_out[b*16 + tid]);
  }

  // df[b,i,j] = sum_h W1[i,h] * (s*W2)[h,j] ; thread -> (i = tid>>1, j0 = (tid&1)*8)
  const int i  = tid >> 1;
  const int j0 = (tid & 1) * 8;
  float acc[8] = {0,0,0,0,0,0,0,0};
  for (int h0 = 0; h0 < 128; h0 += 8){
    const float4* wp = (const float4*)&W1[i*128 + h0];
    float4 wa = wp[0], wb = wp[1];
    float wf[8] = {wa.x, wa.y, wa.z, wa.w, wb.x, wb.y, wb.z, wb.w};
#pragma unroll
    for (int hh = 0; hh < 8; ++hh){
      const float4* sp = (const float4*)&s_sw2[(h0 + hh)*16 + j0];
      float4 A = sp[0], Bv = sp[1];
      float w1 = wf[hh];
      acc[0] += w1*A.x;  acc[1] += w1*A.y;  acc[2] += w1*A.z;  acc[3] += w1*A.w;
      acc[4] += w1*Bv.x; acc[5] += w1*Bv.y; acc[6] += w1*Bv.z; acc[7] += w1*Bv.w;
    }
  }
  f4v v0 = {acc[0], acc[1], acc[2], acc[3]};
  f4v v1 = {acc[4], acc[5], acc[6], acc[7]};
  float* dp = &df_out[b*1024 + i*16 + j0];
  __builtin_nontemporal_store(v0, (f4v*)dp);
  __builtin_nontemporal_store(v1, (f4v*)(dp + 4));
}

extern "C" void kernel_launch(void* const* d_in, const int* in_sizes, int n_in,
                              void* d_out, int out_size, void* d_ws, size_t ws_size,
                              hipStream_t stream)
{
  (void)in_sizes; (void)n_in; (void)out_size; (void)d_ws; (void)ws_size;
  const float* x  = (const float*)d_in[0];
  const float* W1 = (const float*)d_in[1];
  const float* b1 = (const float*)d_in[2];
  const float* W2 = (const float*)d_in[3];
  const float* b2 = (const float*)d_in[4];

  float* out     = (float*)d_out;
  float* f_out   = out;                    // 16384
  float* df_out  = out + 16384;            // 1048576
  float* d2f_out = out + 1064960;          // 67108864

  k2_fused<<<dim3(256, 2), 256, 0, stream>>>(x, W1, b1, W2, d2f_out);
  k1_fdf<<<1024, 128, 0, stream>>>(x, W1, b1, W2, b2, f_out, df_out);
}

// Round 4
// 276.327 us; speedup vs baseline: 1.1105x; 1.0816x over previous
//
#include <hip/hip_runtime.h>
#include <hip/hip_bf16.h>

// B=1024, D_IN=64, H=128, D_OUT=16
// inputs:  fp32  x[1024,64] W1[64,128] b1[128] W2[128,16] b2[16]
// outputs: fp32, flat: f[1024*16] | df[1024*64*16] | d2f[1024*64*64*16]
//
// Math per sample: z = x@W1+b1, a=tanh(z), s=1-a^2, t=-2*a*s
//   f          = a@W2 + b2
//   df[i,j]    = sum_h W1[i,h] s_h W2[h,j]          (exact f32)
//   d2f[k,i,j] = sum_h W1[i,h] W1[k,h] t_h W2[h,j]  (bf16 MFMA, f32 acc)
//
// SINGLE fused kernel, grid (256,2) x 256thr. Block (bg, mb):
//   - d2f for samples b0..b0+3, row-half mb (2048 of 4096 U-rows)
//   - f/df for sample pair {b0+2mb, b0+2mb+1}  (balanced across mb)
// No workspace, one launch. d2f stores are CACHED this round (vs NT in R3):
// nothing is re-read from L2 anymore, and the harness fill demonstrates the
// cached-store path streams at 6.4+ TB/s.

typedef unsigned short u16;
typedef short s8v __attribute__((ext_vector_type(8)));   // 8 bf16 = 4 VGPRs (A/B frag)
typedef float f4v __attribute__((ext_vector_type(4)));

__device__ __forceinline__ u16 f2bf(float f){
  __hip_bfloat16 h = __float2bfloat16(f);   // RNE
  return __builtin_bit_cast(u16, h);
}

#define W1S 132   // padded LDS stride for W1 rows

__global__ __launch_bounds__(256) void k_all(
    const float* __restrict__ x, const float* __restrict__ W1, const float* __restrict__ b1,
    const float* __restrict__ W2, const float* __restrict__ b2,
    float* __restrict__ f_out, float* __restrict__ df_out, float* __restrict__ d2f)
{
  const int tid  = threadIdx.x;
  const int lane = tid & 63;
  const int wave = tid >> 6;
  const int n = lane & 15;      // MFMA position
  const int q = lane >> 4;      // quad (K-block)
  const int b0 = blockIdx.x * 4;
  const int mb = blockIdx.y;    // 0/1: d2f row-half AND f/df sample-pair selector

  __shared__ float sW1[64 * W1S];            // f32 W1, padded rows (33.8 KB)
  __shared__ __align__(16) float sGF[4096];  // phase A: bf16 G swizzled; phase B: f32 s*W2 (16 KB)
  __shared__ float sx[256];                  // phase A: x for 4 samples; phase B: a for 2 samples
  u16* sG = (u16*)sGF;

  // ---- stage W1 (8192 floats) and x ----
#pragma unroll
  for (int v = 0; v < 8; ++v){
    int idx = v*256 + tid;              // float4 index
    int r = idx >> 5;
    int c = (idx & 31) << 2;
    *(f4v*)&sW1[r*W1S + c] = *(const f4v*)&W1[r*128 + c];
  }
  sx[tid] = x[b0*64 + tid];
  __syncthreads();

  // ---- z-pass: all 4 samples -> sG (bf16, XOR-swizzled). Keep a,s of it==mb in regs ----
  float a_keep = 0.f, s_keep = 0.f;
#pragma unroll
  for (int it = 0; it < 2; ++it){
    int idx = it*256 + tid;             // (s,h) item
    int s = idx >> 7;                   // = it*2 + (tid>>7)
    int h = idx & 127;
    float z = b1[h];
#pragma unroll 8
    for (int i = 0; i < 64; ++i) z += sx[s*64 + i] * sW1[i*W1S + h];
    float a = tanhf(z);
    float sd = 1.0f - a*a;              // tanh'
    float t = -2.0f * a * sd;           // tanh''
    if (it == mb){ a_keep = a; s_keep = sd; }
    f4v w2r[4];
#pragma unroll
    for (int v2 = 0; v2 < 4; ++v2) w2r[v2] = *(const f4v*)&W2[h*16 + v2*4];
#pragma unroll
    for (int j = 0; j < 16; ++j){
      int byte = (j*256 + h*2) ^ ((j & 7) << 4);   // bank-spread swizzle
      sG[s*2048 + (byte >> 1)] = f2bf(t * w2r[j >> 2][j & 3]);
    }
  }
  __syncthreads();

  // ---- B-fragments (G^T): lane(n,q), ks -> G[s][j=n][h=q*8+ks*32+e] ----
  s8v bfrag[4][4];
#pragma unroll
  for (int s = 0; s < 4; ++s){
#pragma unroll
    for (int ks = 0; ks < 4; ++ks){
      int byte = (n*256 + q*16 + ks*64) ^ ((n & 7) << 4);
      bfrag[s][ks] = *(const s8v*)&sG[s*2048 + (byte >> 1)];
    }
  }
  __syncthreads();   // all sG reads complete -> safe to repurpose sGF/sx

  // ---- phase B: f and df for samples {b0+2mb, b0+2mb+1} (exact f32, mirrors old k1) ----
  {
    const int ls = tid >> 7;            // 0/1 = local sample
    const int h  = tid & 127;
    float* sF = sGF;                    // [2][128][16] f32 s*W2
    sx[tid] = a_keep;                   // sx[ls*128+h] == sx[tid]
    f4v w2r[4];
#pragma unroll
    for (int v2 = 0; v2 < 4; ++v2) w2r[v2] = *(const f4v*)&W2[h*16 + v2*4];
#pragma unroll
    for (int v2 = 0; v2 < 4; ++v2){
      f4v sv;
#pragma unroll
      for (int e = 0; e < 4; ++e) sv[e] = s_keep * w2r[v2][e];
      *(f4v*)&sF[ls*2048 + h*16 + v2*4] = sv;
    }
    __syncthreads();

    const int sub = tid & 127;
    const int i   = sub >> 1;
    const int j0  = (sub & 1) * 8;
    const int bS  = b0 + 2*mb + ls;
    float acc[8] = {0,0,0,0,0,0,0,0};
    for (int h0 = 0; h0 < 128; h0 += 8){
      const float4* wp = (const float4*)&W1[i*128 + h0];   // global, L1-hot, exact k1 order
      float4 wa = wp[0], wb = wp[1];
      float wf[8] = {wa.x, wa.y, wa.z, wa.w, wb.x, wb.y, wb.z, wb.w};
#pragma unroll
      for (int hh = 0; hh < 8; ++hh){
        const f4v* sp = (const f4v*)&sF[ls*2048 + (h0 + hh)*16 + j0];
        f4v A = sp[0], Bv = sp[1];
        float w1 = wf[hh];
        acc[0] += w1*A[0];  acc[1] += w1*A[1];  acc[2] += w1*A[2];  acc[3] += w1*A[3];
        acc[4] += w1*Bv[0]; acc[5] += w1*Bv[1]; acc[6] += w1*Bv[2]; acc[7] += w1*Bv[3];
      }
    }
    f4v v0 = {acc[0], acc[1], acc[2], acc[3]};
    f4v v1 = {acc[4], acc[5], acc[6], acc[7]};
    float* dp = &df_out[bS*1024 + i*16 + j0];
    __builtin_nontemporal_store(v0, (f4v*)dp);
    __builtin_nontemporal_store(v1, (f4v*)(dp + 4));

    if (sub < 16){
      float accf = b2[sub];
      for (int h2 = 0; h2 < 128; ++h2) accf += sx[ls*128 + h2] * W2[h2*16 + sub];
      __builtin_nontemporal_store(accf, &f_out[bS*16 + sub]);
    }
  }

  // ---- d2f main loop: A-frag on the fly, operand-swapped MFMA, CACHED dwordx4 store ----
  const int R0 = mb*2048 + wave*512;    // each wave: 512 rows = 32 m-tiles
#pragma unroll 2
  for (int mt = 0; mt < 32; ++mt){
    const int rowbase = R0 + mt*16;
    const int r = rowbase + n;          // U row
    const int i = r & 63;
    const int k = r >> 6;
    const float* wi = &sW1[i*W1S];
    const float* wk = &sW1[k*W1S];
    s8v afrag[4];
#pragma unroll
    for (int ks = 0; ks < 4; ++ks){
      int c = q*8 + ks*32;
      f4v ia = *(const f4v*)&wi[c];
      f4v ib = *(const f4v*)&wi[c+4];
      f4v ka = *(const f4v*)&wk[c];
      f4v kb = *(const f4v*)&wk[c+4];
      s8v av;
#pragma unroll
      for (int e = 0; e < 4; ++e) av[e]   = (short)f2bf(ia[e]*ka[e]);
#pragma unroll
      for (int e = 0; e < 4; ++e) av[4+e] = (short)f2bf(ib[e]*kb[e]);
      afrag[ks] = av;
    }
#pragma unroll
    for (int s = 0; s < 4; ++s){
      f4v acc = {0.f, 0.f, 0.f, 0.f};
#pragma unroll
      for (int ks = 0; ks < 4; ++ks)
        acc = __builtin_amdgcn_mfma_f32_16x16x32_bf16(bfrag[s][ks], afrag[ks], acc, 0, 0, 0);
      // D' = (U@G)^T: lane(n,q) holds d2f[b0+s][rowbase+n][q*4 .. q*4+3]
      float* op = d2f + (size_t)(b0 + s)*65536 + (size_t)(rowbase + n)*16 + q*4;
      *(f4v*)op = acc;                  // cached store (A/B vs R3's NT)
    }
  }
}

extern "C" void kernel_launch(void* const* d_in, const int* in_sizes, int n_in,
                              void* d_out, int out_size, void* d_ws, size_t ws_size,
                              hipStream_t stream)
{
  (void)in_sizes; (void)n_in; (void)out_size; (void)d_ws; (void)ws_size;
  const float* x  = (const float*)d_in[0];
  const float* W1 = (const float*)d_in[1];
  const float* b1 = (const float*)d_in[2];
  const float* W2 = (const float*)d_in[3];
  const float* b2 = (const float*)d_in[4];

  float* out     = (float*)d_out;
  float* f_out   = out;                    // 16384
  float* df_out  = out + 16384;            // 1048576
  float* d2f_out = out + 1064960;          // 67108864

  k_all<<<dim3(256, 2), 256, 0, stream>>>(x, W1, b1, W2, b2, f_out, df_out, d2f_out);
}